// Round 22
// baseline (105.768 us; speedup 1.0000x reference)
//
#include <hip/hip_runtime.h>
#include <hip/hip_bf16.h>
#include <cstdint>
#include <cstddef>

typedef __attribute__((ext_vector_type(8))) short short8;
typedef __attribute__((ext_vector_type(4))) float f32x4;
typedef unsigned int u32;
typedef __attribute__((ext_vector_type(4))) u32 u32x4;

#define MFMA(a,b,c) __builtin_amdgcn_mfma_f32_16x16x32_bf16(a,b,c,0,0,0)

__device__ __forceinline__ void gload_lds16(const void* gptr, void* lptr) {
  __builtin_amdgcn_global_load_lds((const __attribute__((address_space(1))) u32*)gptr,
                                   (__attribute__((address_space(3))) u32*)lptr, 16, 0, 0);
}

template<int N> __device__ __forceinline__ void vm_wait() {
  asm volatile("s_waitcnt vmcnt(%0)" :: "n"(N) : "memory");
}

// Raw s_barrier is IntrNoMem in LLVM: fence both sides at IR level (memory-clobber
// asm) and MIR level (sched_barrier) so LDS reads can't hoist above it. (R10-proven)
__device__ __forceinline__ void barrier_sync() {
  asm volatile("" ::: "memory");
  __builtin_amdgcn_s_barrier();
  asm volatile("" ::: "memory");
  __builtin_amdgcn_sched_barrier(0);
}

__device__ __forceinline__ unsigned short f2bf(float f) {
  __hip_bfloat16 h = __float2bfloat16(f);
  return *reinterpret_cast<unsigned short*>(&h);
}

__device__ __forceinline__ short8 ldg8(const unsigned short* p) {
  return *reinterpret_cast<const short8*>(p);
}

__device__ __forceinline__ u32 cvt_pk_bf16(float lo, float hi) {
  u32 r;
  asm("v_cvt_pk_bf16_f32 %0, %1, %2" : "=v"(r) : "v"(lo), "v"(hi));
  return r;
}

// ---------------- fused fp32 -> bf16 conversion (round-9 verbatim) ----------------
__global__ __launch_bounds__(256) void cvt_all_kernel(
    const float* __restrict__ x,
    const float* __restrict__ w0, const float* __restrict__ w1,
    const float* __restrict__ w2, const float* __restrict__ w3,
    unsigned short* __restrict__ xb,
    unsigned short* __restrict__ o0, unsigned short* __restrict__ o1,
    unsigned short* __restrict__ o2, unsigned short* __restrict__ o3)
{
  int id = blockIdx.x * blockDim.x + threadIdx.x;
  const float* in;
  unsigned short* out;
  int idx;
  if (id < 1048576) {
    in = x; out = xb; idx = id;
  } else {
    int r = id - 1048576;
    int z = r >> 18;
    idx = r & 262143;
    in  = (z == 0) ? w0 : (z == 1) ? w1 : (z == 2) ? w2 : w3;
    out = (z == 0) ? o0 : (z == 1) ? o1 : (z == 2) ? o2 : o3;
  }
  float4 f = reinterpret_cast<const float4*>(in)[idx];
  ushort4 o;
  o.x = f2bf(f.x); o.y = f2bf(f.y); o.z = f2bf(f.z); o.w = f2bf(f.w);
  reinterpret_cast<ushort4*>(out)[idx] = o;
}

// ---------------- triple-buffered NT GEMM body: BK=32, LINEAR LDS, ONE barrier/K-step ----------
// Third buffer removes the post-COMPUTE barrier: STAGE((kt+2)%3) overwrites buf (kt-1)%3,
// which every wave finished reading before this iteration's barrier. Cross-wave publish:
// each wave's own vm_wait<NLD> retires its slice of stage(kt); barrier publishes (R10 rule).
template<int BM, int BN, int WM, int WN, bool F32OUT>
__device__ __forceinline__ void gemm2_body(
    const unsigned short* __restrict__ A,
    const unsigned short* __restrict__ W,
    const float* __restrict__ bias,
    unsigned short* __restrict__ outb, float* __restrict__ outf,
    int ldo, float oscale, int m0)
{
  constexpr int K = 1024, BK = 32, NT = K / BK;
  constexpr int NTHR = WM * WN * 64;
  constexpr int FM = BM / (WM * 16);
  constexpr int FN = BN / (WN * 16);
  constexpr int NLA = BM * BK * 2 / (NTHR * 16);
  constexpr int NLB = BN * BK * 2 / (NTHR * 16);
  constexpr int NLD = NLA + NLB;   // loads per thread per tile

  __shared__ unsigned short As[3][BM * BK];
  __shared__ unsigned short Ws[3][BN * BK];

  const int tid = threadIdx.x;
  const int lane = tid & 63;
  const int wave = tid >> 6;
  const int wm = wave / WN, wn = wave % WN;
  const int wr = wm * FM * 16, wc = wn * FN * 16;
  const int lr = lane >> 4, lc = lane & 15;

  f32x4 acc[FM][FN] = {};

  const char* Ab = (const char*)(A + (size_t)m0 * K);
  const char* Wb = (const char*)W;

#define STAGE(buf, k0)                                                            \
  {                                                                               \
    _Pragma("unroll")                                                             \
    for (int i = 0; i < NLA; ++i) {                                               \
      int L = (i * NTHR + tid) * 16;                                              \
      int row = L >> 6;                                                           \
      int col = L & 63;                                                           \
      gload_lds16(Ab + (size_t)row * 2048 + (k0) * 2 + col, (char*)&As[buf][0] + L); \
    }                                                                             \
    _Pragma("unroll")                                                             \
    for (int i = 0; i < NLB; ++i) {                                               \
      int L = (i * NTHR + tid) * 16;                                              \
      int row = L >> 6;                                                           \
      int col = L & 63;                                                           \
      gload_lds16(Wb + (size_t)row * 2048 + (k0) * 2 + col, (char*)&Ws[buf][0] + L); \
    }                                                                             \
  }

#define COMPUTE(buf)                                                              \
  {                                                                               \
    short8 af[FM], bf[FN];                                                        \
    _Pragma("unroll")                                                             \
    for (int m = 0; m < FM; ++m) {                                                \
      int row = wr + m * 16 + lc;                                                 \
      af[m] = *reinterpret_cast<const short8*>(                                   \
          (const char*)&As[buf][0] + row * 64 + lr * 16);                         \
    }                                                                             \
    _Pragma("unroll")                                                             \
    for (int n = 0; n < FN; ++n) {                                                \
      int row = wc + n * 16 + lc;                                                 \
      bf[n] = *reinterpret_cast<const short8*>(                                   \
          (const char*)&Ws[buf][0] + row * 64 + lr * 16);                         \
    }                                                                             \
    __builtin_amdgcn_s_setprio(1);                                                \
    _Pragma("unroll")                                                             \
    for (int m = 0; m < FM; ++m)                                                  \
      _Pragma("unroll")                                                           \
      for (int n = 0; n < FN; ++n)                                                \
        acc[m][n] = MFMA(af[m], bf[n], acc[m][n]);                                \
    __builtin_amdgcn_s_setprio(0);                                                \
  }

  STAGE(0, 0)
  STAGE(1, BK)
  int cur = 0, stg = 2;
#pragma unroll 1
  for (int kt = 0; kt < NT; ++kt) {
    if (kt < NT - 1) { vm_wait<NLD>(); }   // retire own slice of stage(kt); stage(kt+1) in flight
    else            { vm_wait<0>();   }
    barrier_sync();                        // publish all waves' stage(kt) slices
    COMPUTE(cur)
    if (kt + 2 < NT) STAGE(stg, (kt + 2) * BK)   // overwrites buf (kt-1)%3: all reads done pre-barrier
    cur = (cur == 2) ? 0 : cur + 1;
    stg = (stg == 2) ? 0 : stg + 1;
  }

#undef STAGE
#undef COMPUTE

#pragma unroll
  for (int m = 0; m < FM; ++m)
#pragma unroll
    for (int n = 0; n < FN; ++n)
#pragma unroll
      for (int r = 0; r < 4; ++r) {
        int row = m0 + wr + m * 16 + lr * 4 + r;
        int col = wc + n * 16 + lc;
        float v = (acc[m][n][r] + bias[col]) * oscale;
        if (F32OUT) outf[(size_t)row * ldo + col] = v;
        else        outb[(size_t)row * ldo + col] = f2bf(v);
      }
}

// QKV GEMM: per-z 128x128 tiles, 768 blocks = 3 blocks/CU (48KB LDS x3 = 144 <= 160).
__global__ __launch_bounds__(256, 3) void gemm_qkv5(
    const unsigned short* __restrict__ xb,
    const unsigned short* __restrict__ Wqb, const unsigned short* __restrict__ Wkb,
    const unsigned short* __restrict__ Wvb,
    const float* __restrict__ bq, const float* __restrict__ bk, const float* __restrict__ bv,
    unsigned short* __restrict__ Q, unsigned short* __restrict__ Ko, unsigned short* __restrict__ V)
{
  const int i = blockIdx.x;
  const int sw = (i & 7) * 96 + (i >> 3);
  const int z  = sw >> 8;
  const int rr = sw & 255;
  const int m0 = (rr >> 3) * 128;
  const int nr = (rr & 7) * 128;
  const unsigned short* W = ((z == 0) ? Wqb : (z == 1) ? Wkb : Wvb) + (size_t)nr * 1024;
  const float* bias = ((z == 0) ? bq : (z == 1) ? bk : bv) + nr;
  unsigned short* out = ((z == 0) ? Q : (z == 1) ? Ko : V) + nr;
  const float oscale = (z == 0) ? 0.18033688011112042f : 1.0f;
  gemm2_body<128, 128, 2, 2, false>(xb, W, bias, out, nullptr, 1024, oscale, m0);
}

// Out-projection: 64x128 tiles, 512 blocks = 2 blocks/CU (36KB LDS).
__global__ __launch_bounds__(256, 2) void gemm_out3(
    const unsigned short* __restrict__ Y, const unsigned short* __restrict__ Wob,
    const float* __restrict__ bo, float* __restrict__ out)
{
  const int i = blockIdx.x;
  const int sw = (i & 7) * 64 + (i >> 3);
  const int by = sw >> 3;        // 0..63
  const int bx = sw & 7;         // 0..7
  const int m0 = by * 64;
  const int n0 = bx * 128;
  gemm2_body<64, 128, 2, 2, true>(Y, Wob + (size_t)n0 * 1024, bo + n0, nullptr, out + n0,
                                  1024, 1.0f, m0);
}

// ---------------- V transpose (round-4 verbatim) ----------------
__global__ __launch_bounds__(256) void transpose_v(const unsigned short* __restrict__ V,
                                                   unsigned short* __restrict__ VT)
{
  __shared__ unsigned short tile[64 * 68];
  const int tb = blockIdx.x;
  const int bh = blockIdx.y;
  const int b = bh >> 4, h = bh & 15;
  const int tid = threadIdx.x;
  const int t0 = tb * 64;
#pragma unroll
  for (int i = 0; i < 4; ++i) {
    int e = (i * 256 + tid) * 4;
    int t = e >> 6, d = e & 63;
    ushort4 v = *reinterpret_cast<const ushort4*>(&V[((size_t)(b * 2048 + t0 + t)) * 1024 + h * 64 + d]);
    tile[t * 68 + d + 0] = v.x;
    tile[t * 68 + d + 1] = v.y;
    tile[t * 68 + d + 2] = v.z;
    tile[t * 68 + d + 3] = v.w;
  }
  __syncthreads();
#pragma unroll
  for (int i = 0; i < 4; ++i) {
    int e = (i * 256 + tid) * 4;
    int d = e >> 6, tc = e & 63;
    ushort4 w;
    w.x = tile[(tc + 0) * 68 + d];
    w.y = tile[(tc + 1) * 68 + d];
    w.z = tile[(tc + 2) * 68 + d];
    w.w = tile[(tc + 3) * 68 + d];
    *reinterpret_cast<ushort4*>(&VT[((size_t)(bh * 64 + d)) * 2048 + t0 + tc]) = w;
  }
}

// ---------------- flash attention (round-21 verbatim — best measured version) ----------------
__global__ __launch_bounds__(256) void attn_kernel(
    const unsigned short* __restrict__ Q, const unsigned short* __restrict__ K,
    const unsigned short* __restrict__ VT, unsigned short* __restrict__ Y)
{
  __shared__ unsigned short Ks[2][64 * 64];
  __shared__ unsigned short Vs[2][64 * 64];
  __shared__ u32 Pl[4][512];

  const int i   = blockIdx.x;
  const int xcd = i & 7;
  const int j   = i >> 3;
  const int bh  = xcd + 8 * (j & 3);
  const int qb  = 31 - (j >> 2);
  const int b = bh >> 4, h = bh & 15;
  const int tid = threadIdx.x;
  const int wave = tid >> 6;
  const int lane = tid & 63;
  const int lr = lane >> 4;
  const int lc = lane & 15;
  const float M = 4.0f;

  const unsigned short* Kbh = K + (size_t)b * 2048 * 1024 + h * 64;
  const unsigned short* Vbh = VT + (size_t)bh * 64 * 2048;
  u32* pw = Pl[wave];
  const int psw = (lc & 7) << 2;   // per-row xor swizzle (multiple of 4 u32)

  u32 ov = 0x3F803F80u;
  u32x4 ones4 = {ov, ov, ov, ov};
  short8 ones = *reinterpret_cast<short8*>(&ones4);

  const int q0 = qb * 64 + wave * 16;
  const unsigned short* qp = &Q[((size_t)(b * 2048 + q0 + lc)) * 1024 + h * 64 + lr * 8];
  short8 qa0 = ldg8(qp);
  short8 qa1 = ldg8(qp + 32);

  f32x4 o[4] = {};
  f32x4 lacc = {};

  const int nt = qb + 1;
  int cur = 0;

#pragma unroll
  for (int ii = 0; ii < 2; ++ii) {
    int L = (ii * 256 + tid) * 16;
    int row = L >> 7;
    int src = (L & 127) ^ ((row & 7) << 4);
    gload_lds16((const char*)(Kbh + (size_t)row * 1024) + src, (char*)&Ks[0][0] + L);
    gload_lds16((const char*)(Vbh + (size_t)row * 2048) + src, (char*)&Vs[0][0] + L);
  }
  __syncthreads();

  for (int t = 0; t < nt; ++t) {
    if (t + 1 < nt) {
      const int tk1 = (t + 1) * 64;
#pragma unroll
      for (int ii = 0; ii < 2; ++ii) {
        int L = (ii * 256 + tid) * 16;
        int row = L >> 7;
        int src = (L & 127) ^ ((row & 7) << 4);
        gload_lds16((const char*)(Kbh + (size_t)(tk1 + row) * 1024) + src, (char*)&Ks[cur ^ 1][0] + L);
        gload_lds16((const char*)(Vbh + (size_t)row * 2048 + tk1) + src, (char*)&Vs[cur ^ 1][0] + L);
      }
    }

    const int tk0 = t * 64;
    const unsigned short* Kt = Ks[cur];
    const unsigned short* Vt = Vs[cur];

    f32x4 s[4] = {};
#pragma unroll
    for (int kt = 0; kt < 4; ++kt) {
      int row = kt * 16 + lc;
      int sw = (row & 7) << 4;
      short8 kb0 = *reinterpret_cast<const short8*>((const char*)Kt + row * 128 + ((lr * 16) ^ sw));
      short8 kb1 = *reinterpret_cast<const short8*>((const char*)Kt + row * 128 + ((64 + lr * 16) ^ sw));
      __builtin_amdgcn_s_setprio(1);
      s[kt] = MFMA(kb0, qa0, s[kt]);
      s[kt] = MFMA(kb1, qa1, s[kt]);
      __builtin_amdgcn_s_setprio(0);
    }

    const bool diag = (t == qb);
    float p[4][4];
#pragma unroll
    for (int kt = 0; kt < 4; ++kt)
#pragma unroll
      for (int r = 0; r < 4; ++r)
        p[kt][r] = __builtin_amdgcn_exp2f(s[kt][r] - M);
    if (diag) {
#pragma unroll
      for (int kt = 0; kt < 4; ++kt)
#pragma unroll
        for (int r = 0; r < 4; ++r)
          if (tk0 + kt * 16 + lr * 4 + r > q0 + lc) p[kt][r] = 0.f;
    }

#pragma unroll
    for (int kt = 0; kt < 4; ++kt) {
      uint2 w;
      w.x = cvt_pk_bf16(p[kt][0], p[kt][1]);
      w.y = cvt_pk_bf16(p[kt][2], p[kt][3]);
      *reinterpret_cast<uint2*>(&pw[lc * 32 + ((kt * 8 + lr * 2) ^ psw)]) = w;
    }
    short8 pa0 = *reinterpret_cast<const short8*>(&pw[lc * 32 + ((lr * 4) ^ psw)]);
    short8 pa1 = *reinterpret_cast<const short8*>(&pw[lc * 32 + ((16 + lr * 4) ^ psw)]);

    __builtin_amdgcn_s_setprio(1);
    lacc = MFMA(pa0, ones, lacc);
    lacc = MFMA(pa1, ones, lacc);
    __builtin_amdgcn_s_setprio(0);

#pragma unroll
    for (int ntt = 0; ntt < 4; ++ntt) {
      int row = ntt * 16 + lc;
      int sw = (row & 7) << 4;
      short8 v0 = *reinterpret_cast<const short8*>((const char*)Vt + row * 128 + ((lr * 16) ^ sw));
      short8 v1 = *reinterpret_cast<const short8*>((const char*)Vt + row * 128 + ((64 + lr * 16) ^ sw));
      __builtin_amdgcn_s_setprio(1);
      o[ntt] = MFMA(pa0, v0, o[ntt]);
      o[ntt] = MFMA(pa1, v1, o[ntt]);
      __builtin_amdgcn_s_setprio(0);
    }

    __syncthreads();
    cur ^= 1;
  }

  float rl[4];
#pragma unroll
  for (int r = 0; r < 4; ++r) rl[r] = __builtin_amdgcn_rcpf(lacc[r]);
#pragma unroll
  for (int ntt = 0; ntt < 4; ++ntt)
#pragma unroll
    for (int r = 0; r < 4; ++r) {
      float val = o[ntt][r] * rl[r];
      int row = b * 2048 + q0 + lr * 4 + r;
      Y[(size_t)row * 1024 + h * 64 + ntt * 16 + lc] = f2bf(val);
    }
}

// ---------------- host launch ----------------
extern "C" void kernel_launch(void* const* d_in, const int* in_sizes, int n_in,
                              void* d_out, int out_size, void* d_ws, size_t ws_size,
                              hipStream_t stream)
{
  const float* x  = (const float*)d_in[0];
  const float* Wq = (const float*)d_in[1];
  const float* bq = (const float*)d_in[2];
  const float* Wk = (const float*)d_in[3];
  const float* bk = (const float*)d_in[4];
  const float* Wv = (const float*)d_in[5];
  const float* bv = (const float*)d_in[6];
  const float* Wo = (const float*)d_in[7];
  const float* bo = (const float*)d_in[8];
  float* out = (float*)d_out;

  char* ws = (char*)d_ws;
  unsigned short* xb  = (unsigned short*)(ws);
  unsigned short* Wqb = (unsigned short*)(ws + 8388608);
  unsigned short* Wkb = (unsigned short*)(ws + 8388608 + 2097152);
  unsigned short* Wvb = (unsigned short*)(ws + 8388608 + 2 * 2097152);
  unsigned short* Wob = (unsigned short*)(ws + 8388608 + 3 * 2097152);
  unsigned short* Qb  = (unsigned short*)(ws + 16777216);
  unsigned short* Kb  = (unsigned short*)(ws + 16777216 + 8388608);
  unsigned short* Vb  = (unsigned short*)(ws + 16777216 + 2 * 8388608);
  unsigned short* VTb = (unsigned short*)(ws + 16777216 + 3 * 8388608);
  unsigned short* Yb  = (unsigned short*)(ws + 16777216 + 4 * 8388608);

  cvt_all_kernel<<<8192, 256, 0, stream>>>(x, Wq, Wk, Wv, Wo, xb, Wqb, Wkb, Wvb, Wob);

  gemm_qkv5<<<768, 256, 0, stream>>>(xb, Wqb, Wkb, Wvb, bq, bk, bv, Qb, Kb, Vb);
  transpose_v<<<dim3(32, 32), 256, 0, stream>>>(Vb, VTb);
  attn_kernel<<<1024, 256, 0, stream>>>(Qb, Kb, VTb, Yb);
  gemm_out3<<<512, 256, 0, stream>>>(Yb, Wob, bo, out);
}

// Round 23
// 103.486 us; speedup vs baseline: 1.0220x; 1.0220x over previous
//
#include <hip/hip_runtime.h>
#include <hip/hip_bf16.h>
#include <cstdint>
#include <cstddef>

typedef __attribute__((ext_vector_type(8))) short short8;
typedef __attribute__((ext_vector_type(4))) float f32x4;
typedef unsigned int u32;
typedef __attribute__((ext_vector_type(4))) u32 u32x4;

#define MFMA(a,b,c) __builtin_amdgcn_mfma_f32_16x16x32_bf16(a,b,c,0,0,0)

__device__ __forceinline__ void gload_lds16(const void* gptr, void* lptr) {
  __builtin_amdgcn_global_load_lds((const __attribute__((address_space(1))) u32*)gptr,
                                   (__attribute__((address_space(3))) u32*)lptr, 16, 0, 0);
}

template<int N> __device__ __forceinline__ void vm_wait() {
  asm volatile("s_waitcnt vmcnt(%0)" :: "n"(N) : "memory");
}

// Raw s_barrier is IntrNoMem in LLVM: fence both sides at IR level (memory-clobber
// asm) and MIR level (sched_barrier) so LDS reads can't hoist above it. (R10-proven)
__device__ __forceinline__ void barrier_sync() {
  asm volatile("" ::: "memory");
  __builtin_amdgcn_s_barrier();
  asm volatile("" ::: "memory");
  __builtin_amdgcn_sched_barrier(0);
}

__device__ __forceinline__ unsigned short f2bf(float f) {
  __hip_bfloat16 h = __float2bfloat16(f);
  return *reinterpret_cast<unsigned short*>(&h);
}

__device__ __forceinline__ short8 ldg8(const unsigned short* p) {
  return *reinterpret_cast<const short8*>(p);
}

__device__ __forceinline__ u32 cvt_pk_bf16(float lo, float hi) {
  u32 r;
  asm("v_cvt_pk_bf16_f32 %0, %1, %2" : "=v"(r) : "v"(lo), "v"(hi));
  return r;
}

// ---------------- fused fp32 -> bf16 conversion (round-9 verbatim) ----------------
__global__ __launch_bounds__(256) void cvt_all_kernel(
    const float* __restrict__ x,
    const float* __restrict__ w0, const float* __restrict__ w1,
    const float* __restrict__ w2, const float* __restrict__ w3,
    unsigned short* __restrict__ xb,
    unsigned short* __restrict__ o0, unsigned short* __restrict__ o1,
    unsigned short* __restrict__ o2, unsigned short* __restrict__ o3)
{
  int id = blockIdx.x * blockDim.x + threadIdx.x;
  const float* in;
  unsigned short* out;
  int idx;
  if (id < 1048576) {
    in = x; out = xb; idx = id;
  } else {
    int r = id - 1048576;
    int z = r >> 18;
    idx = r & 262143;
    in  = (z == 0) ? w0 : (z == 1) ? w1 : (z == 2) ? w2 : w3;
    out = (z == 0) ? o0 : (z == 1) ? o1 : (z == 2) ? o2 : o3;
  }
  float4 f = reinterpret_cast<const float4*>(in)[idx];
  ushort4 o;
  o.x = f2bf(f.x); o.y = f2bf(f.y); o.z = f2bf(f.z); o.w = f2bf(f.w);
  reinterpret_cast<ushort4*>(out)[idx] = o;
}

// ---------------- triple-buffered NT GEMM body (R22-proven) + optional transposed-V epilogue ----
// outvt != nullptr (wave-uniform): write bf16 TRANSPOSED into VT[b*1024+gcol][row&2047]
// (VT_row = (b*16+h)*64+d = b*1024 + gcol). Used by the z==2 (V) QKV blocks to absorb
// transpose_v. Each block covers a dense 128x128 VT patch -> L2 write-combining ~1x.
template<int BM, int BN, int WM, int WN, bool F32OUT>
__device__ __forceinline__ void gemm2_body(
    const unsigned short* __restrict__ A,
    const unsigned short* __restrict__ W,
    const float* __restrict__ bias,
    unsigned short* __restrict__ outb, float* __restrict__ outf,
    int ldo, float oscale, int m0,
    unsigned short* __restrict__ outvt = nullptr, int n0g = 0)
{
  constexpr int K = 1024, BK = 32, NT = K / BK;
  constexpr int NTHR = WM * WN * 64;
  constexpr int FM = BM / (WM * 16);
  constexpr int FN = BN / (WN * 16);
  constexpr int NLA = BM * BK * 2 / (NTHR * 16);
  constexpr int NLB = BN * BK * 2 / (NTHR * 16);
  constexpr int NLD = NLA + NLB;   // loads per thread per tile

  __shared__ unsigned short As[3][BM * BK];
  __shared__ unsigned short Ws[3][BN * BK];

  const int tid = threadIdx.x;
  const int lane = tid & 63;
  const int wave = tid >> 6;
  const int wm = wave / WN, wn = wave % WN;
  const int wr = wm * FM * 16, wc = wn * FN * 16;
  const int lr = lane >> 4, lc = lane & 15;

  f32x4 acc[FM][FN] = {};

  const char* Ab = (const char*)(A + (size_t)m0 * K);
  const char* Wb = (const char*)W;

#define STAGE(buf, k0)                                                            \
  {                                                                               \
    _Pragma("unroll")                                                             \
    for (int i = 0; i < NLA; ++i) {                                               \
      int L = (i * NTHR + tid) * 16;                                              \
      int row = L >> 6;                                                           \
      int col = L & 63;                                                           \
      gload_lds16(Ab + (size_t)row * 2048 + (k0) * 2 + col, (char*)&As[buf][0] + L); \
    }                                                                             \
    _Pragma("unroll")                                                             \
    for (int i = 0; i < NLB; ++i) {                                               \
      int L = (i * NTHR + tid) * 16;                                              \
      int row = L >> 6;                                                           \
      int col = L & 63;                                                           \
      gload_lds16(Wb + (size_t)row * 2048 + (k0) * 2 + col, (char*)&Ws[buf][0] + L); \
    }                                                                             \
  }

#define COMPUTE(buf)                                                              \
  {                                                                               \
    short8 af[FM], bf[FN];                                                        \
    _Pragma("unroll")                                                             \
    for (int m = 0; m < FM; ++m) {                                                \
      int row = wr + m * 16 + lc;                                                 \
      af[m] = *reinterpret_cast<const short8*>(                                   \
          (const char*)&As[buf][0] + row * 64 + lr * 16);                         \
    }                                                                             \
    _Pragma("unroll")                                                             \
    for (int n = 0; n < FN; ++n) {                                                \
      int row = wc + n * 16 + lc;                                                 \
      bf[n] = *reinterpret_cast<const short8*>(                                   \
          (const char*)&Ws[buf][0] + row * 64 + lr * 16);                         \
    }                                                                             \
    __builtin_amdgcn_s_setprio(1);                                                \
    _Pragma("unroll")                                                             \
    for (int m = 0; m < FM; ++m)                                                  \
      _Pragma("unroll")                                                           \
      for (int n = 0; n < FN; ++n)                                                \
        acc[m][n] = MFMA(af[m], bf[n], acc[m][n]);                                \
    __builtin_amdgcn_s_setprio(0);                                                \
  }

  STAGE(0, 0)
  STAGE(1, BK)
  int cur = 0, stg = 2;
#pragma unroll 1
  for (int kt = 0; kt < NT; ++kt) {
    if (kt < NT - 1) { vm_wait<NLD>(); }   // retire own slice of stage(kt); stage(kt+1) in flight
    else            { vm_wait<0>();   }
    barrier_sync();                        // publish all waves' stage(kt) slices
    COMPUTE(cur)
    if (kt + 2 < NT) STAGE(stg, (kt + 2) * BK)   // overwrites buf (kt-1)%3: all reads done pre-barrier
    cur = (cur == 2) ? 0 : cur + 1;
    stg = (stg == 2) ? 0 : stg + 1;
  }

#undef STAGE
#undef COMPUTE

  if (!F32OUT && outvt != nullptr) {
    // transposed-V epilogue: VT[b*1024 + gcol][t], b = row>>11, t = row&2047
#pragma unroll
    for (int m = 0; m < FM; ++m)
#pragma unroll
      for (int n = 0; n < FN; ++n)
#pragma unroll
        for (int r = 0; r < 4; ++r) {
          int row = m0 + wr + m * 16 + lr * 4 + r;
          int gcol = n0g + wc + n * 16 + lc;
          float v = (acc[m][n][r] + bias[wc + n * 16 + lc]) * oscale;
          int bb = row >> 11, tt = row & 2047;
          outvt[(size_t)(bb * 1024 + gcol) * 2048 + tt] = f2bf(v);
        }
    return;
  }

#pragma unroll
  for (int m = 0; m < FM; ++m)
#pragma unroll
    for (int n = 0; n < FN; ++n)
#pragma unroll
      for (int r = 0; r < 4; ++r) {
        int row = m0 + wr + m * 16 + lr * 4 + r;
        int col = wc + n * 16 + lc;
        float v = (acc[m][n][r] + bias[col]) * oscale;
        if (F32OUT) outf[(size_t)row * ldo + col] = v;
        else        outb[(size_t)row * ldo + col] = f2bf(v);
      }
}

// QKV GEMM: per-z 128x128 tiles, 768 blocks = 3 blocks/CU (48KB LDS x3 = 144 <= 160).
// z==2 (V) blocks write TRANSPOSED directly into VT -> transpose_v kernel eliminated.
__global__ __launch_bounds__(256, 3) void gemm_qkv5(
    const unsigned short* __restrict__ xb,
    const unsigned short* __restrict__ Wqb, const unsigned short* __restrict__ Wkb,
    const unsigned short* __restrict__ Wvb,
    const float* __restrict__ bq, const float* __restrict__ bk, const float* __restrict__ bv,
    unsigned short* __restrict__ Q, unsigned short* __restrict__ Ko,
    unsigned short* __restrict__ VT)
{
  const int i = blockIdx.x;
  const int sw = (i & 7) * 96 + (i >> 3);
  const int z  = sw >> 8;
  const int rr = sw & 255;
  const int m0 = (rr >> 3) * 128;
  const int nr = (rr & 7) * 128;
  const unsigned short* W = ((z == 0) ? Wqb : (z == 1) ? Wkb : Wvb) + (size_t)nr * 1024;
  const float* bias = ((z == 0) ? bq : (z == 1) ? bk : bv) + nr;
  const float oscale = (z == 0) ? 0.18033688011112042f : 1.0f;
  if (z == 2) {
    gemm2_body<128, 128, 2, 2, false>(xb, W, bias, nullptr, nullptr, 1024, oscale, m0, VT, nr);
  } else {
    unsigned short* out = ((z == 0) ? Q : Ko) + nr;
    gemm2_body<128, 128, 2, 2, false>(xb, W, bias, out, nullptr, 1024, oscale, m0);
  }
}

// Out-projection: 64x128 tiles, 512 blocks = 2 blocks/CU (36KB LDS).
__global__ __launch_bounds__(256, 2) void gemm_out3(
    const unsigned short* __restrict__ Y, const unsigned short* __restrict__ Wob,
    const float* __restrict__ bo, float* __restrict__ out)
{
  const int i = blockIdx.x;
  const int sw = (i & 7) * 64 + (i >> 3);
  const int by = sw >> 3;        // 0..63
  const int bx = sw & 7;         // 0..7
  const int m0 = by * 64;
  const int n0 = bx * 128;
  gemm2_body<64, 128, 2, 2, true>(Y, Wob + (size_t)n0 * 1024, bo + n0, nullptr, out + n0,
                                  1024, 1.0f, m0);
}

// ---------------- flash attention (round-21 verbatim — best measured version) ----------------
__global__ __launch_bounds__(256) void attn_kernel(
    const unsigned short* __restrict__ Q, const unsigned short* __restrict__ K,
    const unsigned short* __restrict__ VT, unsigned short* __restrict__ Y)
{
  __shared__ unsigned short Ks[2][64 * 64];
  __shared__ unsigned short Vs[2][64 * 64];
  __shared__ u32 Pl[4][512];

  const int i   = blockIdx.x;
  const int xcd = i & 7;
  const int j   = i >> 3;
  const int bh  = xcd + 8 * (j & 3);
  const int qb  = 31 - (j >> 2);
  const int b = bh >> 4, h = bh & 15;
  const int tid = threadIdx.x;
  const int wave = tid >> 6;
  const int lane = tid & 63;
  const int lr = lane >> 4;
  const int lc = lane & 15;
  const float M = 4.0f;

  const unsigned short* Kbh = K + (size_t)b * 2048 * 1024 + h * 64;
  const unsigned short* Vbh = VT + (size_t)bh * 64 * 2048;
  u32* pw = Pl[wave];
  const int psw = (lc & 7) << 2;   // per-row xor swizzle (multiple of 4 u32)

  u32 ov = 0x3F803F80u;
  u32x4 ones4 = {ov, ov, ov, ov};
  short8 ones = *reinterpret_cast<short8*>(&ones4);

  const int q0 = qb * 64 + wave * 16;
  const unsigned short* qp = &Q[((size_t)(b * 2048 + q0 + lc)) * 1024 + h * 64 + lr * 8];
  short8 qa0 = ldg8(qp);
  short8 qa1 = ldg8(qp + 32);

  f32x4 o[4] = {};
  f32x4 lacc = {};

  const int nt = qb + 1;
  int cur = 0;

#pragma unroll
  for (int ii = 0; ii < 2; ++ii) {
    int L = (ii * 256 + tid) * 16;
    int row = L >> 7;
    int src = (L & 127) ^ ((row & 7) << 4);
    gload_lds16((const char*)(Kbh + (size_t)row * 1024) + src, (char*)&Ks[0][0] + L);
    gload_lds16((const char*)(Vbh + (size_t)row * 2048) + src, (char*)&Vs[0][0] + L);
  }
  __syncthreads();

  for (int t = 0; t < nt; ++t) {
    if (t + 1 < nt) {
      const int tk1 = (t + 1) * 64;
#pragma unroll
      for (int ii = 0; ii < 2; ++ii) {
        int L = (ii * 256 + tid) * 16;
        int row = L >> 7;
        int src = (L & 127) ^ ((row & 7) << 4);
        gload_lds16((const char*)(Kbh + (size_t)(tk1 + row) * 1024) + src, (char*)&Ks[cur ^ 1][0] + L);
        gload_lds16((const char*)(Vbh + (size_t)row * 2048 + tk1) + src, (char*)&Vs[cur ^ 1][0] + L);
      }
    }

    const int tk0 = t * 64;
    const unsigned short* Kt = Ks[cur];
    const unsigned short* Vt = Vs[cur];

    f32x4 s[4] = {};
#pragma unroll
    for (int kt = 0; kt < 4; ++kt) {
      int row = kt * 16 + lc;
      int sw = (row & 7) << 4;
      short8 kb0 = *reinterpret_cast<const short8*>((const char*)Kt + row * 128 + ((lr * 16) ^ sw));
      short8 kb1 = *reinterpret_cast<const short8*>((const char*)Kt + row * 128 + ((64 + lr * 16) ^ sw));
      __builtin_amdgcn_s_setprio(1);
      s[kt] = MFMA(kb0, qa0, s[kt]);
      s[kt] = MFMA(kb1, qa1, s[kt]);
      __builtin_amdgcn_s_setprio(0);
    }

    const bool diag = (t == qb);
    float p[4][4];
#pragma unroll
    for (int kt = 0; kt < 4; ++kt)
#pragma unroll
      for (int r = 0; r < 4; ++r)
        p[kt][r] = __builtin_amdgcn_exp2f(s[kt][r] - M);
    if (diag) {
#pragma unroll
      for (int kt = 0; kt < 4; ++kt)
#pragma unroll
        for (int r = 0; r < 4; ++r)
          if (tk0 + kt * 16 + lr * 4 + r > q0 + lc) p[kt][r] = 0.f;
    }

#pragma unroll
    for (int kt = 0; kt < 4; ++kt) {
      uint2 w;
      w.x = cvt_pk_bf16(p[kt][0], p[kt][1]);
      w.y = cvt_pk_bf16(p[kt][2], p[kt][3]);
      *reinterpret_cast<uint2*>(&pw[lc * 32 + ((kt * 8 + lr * 2) ^ psw)]) = w;
    }
    short8 pa0 = *reinterpret_cast<const short8*>(&pw[lc * 32 + ((lr * 4) ^ psw)]);
    short8 pa1 = *reinterpret_cast<const short8*>(&pw[lc * 32 + ((16 + lr * 4) ^ psw)]);

    __builtin_amdgcn_s_setprio(1);
    lacc = MFMA(pa0, ones, lacc);
    lacc = MFMA(pa1, ones, lacc);
    __builtin_amdgcn_s_setprio(0);

#pragma unroll
    for (int ntt = 0; ntt < 4; ++ntt) {
      int row = ntt * 16 + lc;
      int sw = (row & 7) << 4;
      short8 v0 = *reinterpret_cast<const short8*>((const char*)Vt + row * 128 + ((lr * 16) ^ sw));
      short8 v1 = *reinterpret_cast<const short8*>((const char*)Vt + row * 128 + ((64 + lr * 16) ^ sw));
      __builtin_amdgcn_s_setprio(1);
      o[ntt] = MFMA(pa0, v0, o[ntt]);
      o[ntt] = MFMA(pa1, v1, o[ntt]);
      __builtin_amdgcn_s_setprio(0);
    }

    __syncthreads();
    cur ^= 1;
  }

  float rl[4];
#pragma unroll
  for (int r = 0; r < 4; ++r) rl[r] = __builtin_amdgcn_rcpf(lacc[r]);
#pragma unroll
  for (int ntt = 0; ntt < 4; ++ntt)
#pragma unroll
    for (int r = 0; r < 4; ++r) {
      float val = o[ntt][r] * rl[r];
      int row = b * 2048 + q0 + lr * 4 + r;
      Y[(size_t)row * 1024 + h * 64 + ntt * 16 + lc] = f2bf(val);
    }
}

// ---------------- host launch ----------------
extern "C" void kernel_launch(void* const* d_in, const int* in_sizes, int n_in,
                              void* d_out, int out_size, void* d_ws, size_t ws_size,
                              hipStream_t stream)
{
  const float* x  = (const float*)d_in[0];
  const float* Wq = (const float*)d_in[1];
  const float* bq = (const float*)d_in[2];
  const float* Wk = (const float*)d_in[3];
  const float* bk = (const float*)d_in[4];
  const float* Wv = (const float*)d_in[5];
  const float* bv = (const float*)d_in[6];
  const float* Wo = (const float*)d_in[7];
  const float* bo = (const float*)d_in[8];
  float* out = (float*)d_out;

  char* ws = (char*)d_ws;
  unsigned short* xb  = (unsigned short*)(ws);
  unsigned short* Wqb = (unsigned short*)(ws + 8388608);
  unsigned short* Wkb = (unsigned short*)(ws + 8388608 + 2097152);
  unsigned short* Wvb = (unsigned short*)(ws + 8388608 + 2 * 2097152);
  unsigned short* Wob = (unsigned short*)(ws + 8388608 + 3 * 2097152);
  unsigned short* Qb  = (unsigned short*)(ws + 16777216);
  unsigned short* Kb  = (unsigned short*)(ws + 16777216 + 8388608);
  unsigned short* VTb = (unsigned short*)(ws + 16777216 + 3 * 8388608);
  unsigned short* Yb  = (unsigned short*)(ws + 16777216 + 4 * 8388608);

  cvt_all_kernel<<<8192, 256, 0, stream>>>(x, Wq, Wk, Wv, Wo, xb, Wqb, Wkb, Wvb, Wob);

  gemm_qkv5<<<768, 256, 0, stream>>>(xb, Wqb, Wkb, Wvb, bq, bk, bv, Qb, Kb, VTb);
  attn_kernel<<<1024, 256, 0, stream>>>(Qb, Kb, VTb, Yb);
  gemm_out3<<<512, 256, 0, stream>>>(Yb, Wob, bo, out);
}